// Round 1
// baseline (85.328 us; speedup 1.0000x reference)
//
#include <hip/hip_runtime.h>
#include <math.h>

#define BB 512
#define SS 200
#define DD 64
#define VV 100000

__device__ __forceinline__ float lane_bcast(float v, int l) {
    return __uint_as_float(__builtin_amdgcn_readlane(__float_as_uint(v), l));
}

__device__ __forceinline__ float gauss_pdf(float xx, float mu, float sg) {
    float z = (xx - mu) / sg;
    return expf(-0.5f * z * z - logf(sg) - 0.9189385332046727f);
}

__global__ __launch_bounds__(256) void fused_kernel(
    const float* __restrict__ x, const int* __restrict__ x_ids,
    const float* __restrict__ tg, const int* __restrict__ cla,
    const float* __restrict__ Wq, const float* __restrict__ bq,
    const float* __restrict__ Wk, const float* __restrict__ bk,
    const float* __restrict__ wv, const float* __restrict__ bv,
    const float* __restrict__ theta, float* __restrict__ out)
{
    const int b    = blockIdx.x;
    const int tid  = threadIdx.x;
    const int lane = tid & 63;
    const int wave = tid >> 6;

    __shared__ float sTh[17];
    __shared__ float sx0[DD];
    __shared__ float sKp[4][DD];
    __shared__ float sScore[SS];
    __shared__ float sRed[8];

    if (tid < 17) sTh[tid] = theta[tid];
    if (tid < DD) sx0[tid] = x[(size_t)b * SS * DD + tid];
    __syncthreads();

    // k_b partials: wave w covers j in [w*16, w*16+16); lane = output dim d
    {
        float acc = 0.f;
        #pragma unroll
        for (int jj = 0; jj < 16; ++jj) {
            int j = wave * 16 + jj;
            acc = fmaf(sx0[j], Wk[j * DD + lane], acc);
        }
        sKp[wave][lane] = acc;
    }

    // Wq column for this lane (d = lane), kept in 64 VGPRs, reused for all s
    float wqc[DD];
    #pragma unroll
    for (int j = 0; j < DD; ++j) wqc[j] = Wq[j * DD + lane];
    const float wvl = wv[lane];
    const float bvv = bv[0];

    __syncthreads();

    const float kpl = sKp[0][lane] + sKp[1][lane] + sKp[2][lane] + sKp[3][lane]
                    + bk[lane] + bq[lane];   // (k + bq + bk-part), folded biases

    // Issue zero-stores for this block's own output row. No barrier here:
    // they drain in the background under the score compute; the
    // __syncthreads after the score loop (vmcnt(0) drain) makes them
    // visible before any atomics touch the row.
    float4* __restrict__ orow4 = (float4*)(out + (size_t)b * VV);
    const float4 z4 = make_float4(0.f, 0.f, 0.f, 0.f);
    for (int i = tid; i < VV / 4; i += 256) orow4[i] = z4;

    // scores: one wave per sequence position s
    const float* __restrict__ xb = x + (size_t)b * SS * DD;
    for (int s = wave; s < SS; s += 4) {
        float xs = xb[s * DD + lane];   // lane j holds x[b,s,j]; coalesced 256B
        float acc = 0.f;
        #pragma unroll
        for (int j = 0; j < DD; ++j)
            acc = fmaf(lane_bcast(xs, j), wqc[j], acc);  // readlane -> SGPR src
        float f = tanhf(acc + kpl);     // feat[d], d = lane
        float v = f * wvl;
        #pragma unroll
        for (int off = 32; off > 0; off >>= 1) v += __shfl_xor(v, off);
        if (lane == 0) {
            int id = x_ids[b * SS + s];
            sScore[s] = (id == 0 || id == 1) ? -INFINITY : (v + bvv);
        }
    }
    __syncthreads();   // scores ready; zero-stores drained & visible in-block

    // block softmax over 200 scores (tid == s)
    float sc = (tid < SS) ? sScore[tid] : -INFINITY;
    float m = sc;
    #pragma unroll
    for (int off = 32; off > 0; off >>= 1) m = fmaxf(m, __shfl_xor(m, off));
    if (lane == 0) sRed[wave] = m;
    __syncthreads();
    const float M = fmaxf(fmaxf(sRed[0], sRed[1]), fmaxf(sRed[2], sRed[3]));
    float e = (tid < SS) ? expf(sc - M) : 0.f;
    float ssum = e;
    #pragma unroll
    for (int off = 32; off > 0; off >>= 1) ssum += __shfl_xor(ssum, off);
    if (lane == 0) sRed[4 + wave] = ssum;   // disjoint slots from max phase
    __syncthreads();
    const float Z = sRed[4] + sRed[5] + sRed[6] + sRed[7];

    float* __restrict__ orow = out + (size_t)b * VV;
    const float wpg = sTh[6];

    // p_repeat scatter: (1-w) * att  (masked entries have e == 0 -> no-op)
    if (tid < SS && e > 0.f) {
        int id = x_ids[b * SS + tid];
        atomicAdd(orow + id, (1.f - wpg) * (e / Z));
    }

    // p_gap scatter: w * (g0 + g1 + g2) at ids x_ids[:, 1:]
    if (tid < SS - 1) {
        float t  = tg[b * (SS - 1) + tid];
        int   c  = cla[b * (SS - 1) + tid];
        float c0 = (c == 0) ? t : 180.f;
        float c1 = (c == 1) ? t : 180.f;
        float c2 = (c == 2) ? t : 180.f;
        float g = sTh[0] * gauss_pdf(c0, sTh[7],  sTh[8])
                + sTh[1] * gauss_pdf(c1, sTh[9],  sTh[10])
                + sTh[2] * gauss_pdf(c1, sTh[11], sTh[12])
                + sTh[3] * gauss_pdf(c2, sTh[13], sTh[14])
                + sTh[4] * powf(c2, sTh[15]);
        int id = x_ids[b * SS + tid + 1];
        atomicAdd(orow + id, wpg * g);
    }
}

extern "C" void kernel_launch(void* const* d_in, const int* in_sizes, int n_in,
                              void* d_out, int out_size, void* d_ws, size_t ws_size,
                              hipStream_t stream) {
    const float* x     = (const float*)d_in[0];
    const int*   x_ids = (const int*)d_in[1];
    const float* tgp   = (const float*)d_in[2];
    const int*   cl    = (const int*)d_in[3];
    const float* Wq    = (const float*)d_in[4];
    const float* bq    = (const float*)d_in[5];
    const float* Wk    = (const float*)d_in[6];
    const float* bk    = (const float*)d_in[7];
    const float* wv    = (const float*)d_in[8];
    const float* bv    = (const float*)d_in[9];
    const float* th    = (const float*)d_in[10];
    float* out = (float*)d_out;

    hipLaunchKernelGGL(fused_kernel, dim3(BB), dim3(256), 0, stream,
                       x, x_ids, tgp, cl, Wq, bq, Wk, bk, wv, bv, th, out);
}